// Round 1
// baseline (121.621 us; speedup 1.0000x reference)
//
#include <hip/hip_runtime.h>
#include <hip/hip_bf16.h>

#define N 8192
#define D 512
#define BM 128
#define BN 128
#define BK 64
#define NCB (N / BN)   // 64 column blocks
#define NKT (D / BK)   // 8 K tiles
#define INVT 14.285714285714286f

typedef __attribute__((ext_vector_type(8))) short bf16x8;
typedef __attribute__((ext_vector_type(4))) float f32x4;
typedef __attribute__((ext_vector_type(8))) unsigned short u16x8;

__device__ __forceinline__ unsigned short f2bf(float f) {
  __hip_bfloat16 h = __float2bfloat16(f);
  return *reinterpret_cast<unsigned short*>(&h);
}

// ---------------- kernel 1: L2-normalize rows, cast to bf16 ----------------
__global__ __launch_bounds__(64) void k_normalize(const float* __restrict__ x,
                                                  unsigned short* __restrict__ fb) {
  const int row = blockIdx.x;
  const int lane = threadIdx.x;
  const float* rp = x + (size_t)row * D + lane * 8;
  float4 v0 = *reinterpret_cast<const float4*>(rp);
  float4 v1 = *reinterpret_cast<const float4*>(rp + 4);
  float s = v0.x*v0.x + v0.y*v0.y + v0.z*v0.z + v0.w*v0.w
          + v1.x*v1.x + v1.y*v1.y + v1.z*v1.z + v1.w*v1.w;
  #pragma unroll
  for (int m = 1; m < 64; m <<= 1) s += __shfl_xor(s, m);
  float inv = 1.0f / fmaxf(sqrtf(s), 1e-12f);
  u16x8 o;
  o[0] = f2bf(v0.x*inv); o[1] = f2bf(v0.y*inv); o[2] = f2bf(v0.z*inv); o[3] = f2bf(v0.w*inv);
  o[4] = f2bf(v1.x*inv); o[5] = f2bf(v1.y*inv); o[6] = f2bf(v1.z*inv); o[7] = f2bf(v1.w*inv);
  *reinterpret_cast<u16x8*>(fb + (size_t)row * D + lane * 8) = o;
}

// ---------------- kernel 2: label histogram (pos counts) ----------------
__global__ void k_hist(const int* __restrict__ labels, int* __restrict__ hist) {
  __shared__ int h[128];
  int tid = threadIdx.x;
  if (tid < 128) h[tid] = 0;
  __syncthreads();
  for (int i = tid; i < N; i += blockDim.x) atomicAdd(&h[labels[i]], 1);
  __syncthreads();
  if (tid < 128) hist[tid] = h[tid];
}

// ---------------- kernel 3: fused GEMM + exp-rowsum + masked-sum ----------------
#define GLOAD_LDS16(g, l) __builtin_amdgcn_global_load_lds( \
    (const __attribute__((address_space(1))) unsigned int*)(g), \
    (__attribute__((address_space(3))) unsigned int*)(l), 16, 0, 0)

__global__ __launch_bounds__(256, 2) void k_gemm(
    const unsigned short* __restrict__ fb, const int* __restrict__ labels,
    float* __restrict__ part_e, float* __restrict__ part_p) {
  __shared__ __align__(16) short As[BM * BK];
  __shared__ __align__(16) short Bs[BN * BK];
  __shared__ float e_part[2][BM];
  __shared__ float p_part[2][BM];
  __shared__ int labR[BM];
  __shared__ int labC[BN];

  const int tid = threadIdx.x;
  const int lane = tid & 63;
  const int w = tid >> 6;
  const int wr = w >> 1, wc = w & 1;
  const int bx = blockIdx.x, by = blockIdx.y;
  const int rowA0 = by * BM, rowB0 = bx * BN;

  if (tid < BM) labR[tid] = labels[rowA0 + tid];
  else          labC[tid - BM] = labels[rowB0 + (tid - BM)];

  f32x4 acc[4][4] = {};
  const int sslot = tid & 7;

  for (int kt = 0; kt < NKT; ++kt) {
    if (kt) __syncthreads();            // all waves done reading previous tile
    const int kbase = kt * BK;
    // stage A (rows of this row-block) and B (rows of this col-block).
    // LDS dest is linear (wave-uniform base + lane*16); the XOR swizzle is
    // applied by permuting the global SOURCE k-slot (G21: both-sides-or-neither).
    #pragma unroll
    for (int it = 0; it < 4; ++it) {
      int r = (it * 256 + tid) >> 3;                 // 0..127
      int kcol = ((sslot ^ (r & 7)) << 3) + kbase;   // pre-swizzled source k
      GLOAD_LDS16(fb + (size_t)(rowA0 + r) * D + kcol,
                  (char*)As + it * 4096 + w * 1024);
    }
    #pragma unroll
    for (int it = 0; it < 4; ++it) {
      int r = (it * 256 + tid) >> 3;
      int kcol = ((sslot ^ (r & 7)) << 3) + kbase;
      GLOAD_LDS16(fb + (size_t)(rowB0 + r) * D + kcol,
                  (char*)Bs + it * 4096 + w * 1024);
    }
    __syncthreads();

    #pragma unroll
    for (int kk = 0; kk < BK; kk += 32) {
      bf16x8 af[4], bg[4];
      #pragma unroll
      for (int m = 0; m < 4; ++m) {
        int ar = wr * 64 + m * 16 + (lane & 15);
        int kb = (kk + ((lane >> 4) << 3)) * 2;
        af[m] = *reinterpret_cast<const bf16x8*>(
            (const char*)As + ar * 128 + (kb ^ ((ar & 7) << 4)));
      }
      #pragma unroll
      for (int n = 0; n < 4; ++n) {
        int br = wc * 64 + n * 16 + (lane & 15);
        int kb = (kk + ((lane >> 4) << 3)) * 2;
        bg[n] = *reinterpret_cast<const bf16x8*>(
            (const char*)Bs + br * 128 + (kb ^ ((br & 7) << 4)));
      }
      #pragma unroll
      for (int m = 0; m < 4; ++m)
        #pragma unroll
        for (int n = 0; n < 4; ++n)
          acc[m][n] = __builtin_amdgcn_mfma_f32_16x16x32_bf16(af[m], bg[n], acc[m][n], 0, 0, 0);
    }
  }

  // ---- fused epilogue: S = acc/T; accumulate exp-sum and masked-sum per row ----
  float esum[4][4] = {};
  float psum[4][4] = {};
  int lr[4][4];
  #pragma unroll
  for (int m = 0; m < 4; ++m)
    #pragma unroll
    for (int r = 0; r < 4; ++r)
      lr[m][r] = labR[wr * 64 + m * 16 + ((lane >> 4) << 2) + r];

  #pragma unroll
  for (int n = 0; n < 4; ++n) {
    int lc = labC[wc * 64 + n * 16 + (lane & 15)];
    #pragma unroll
    for (int m = 0; m < 4; ++m)
      #pragma unroll
      for (int r = 0; r < 4; ++r) {
        float s = acc[m][n][r] * INVT;
        esum[m][r] += __expf(s);
        psum[m][r] += (lr[m][r] == lc) ? s : 0.0f;
      }
  }

  // cross-lane reduce over the 16 columns held by each 16-lane group
  #pragma unroll
  for (int m = 0; m < 4; ++m)
    #pragma unroll
    for (int r = 0; r < 4; ++r) {
      float e = esum[m][r], p = psum[m][r];
      #pragma unroll
      for (int msk = 1; msk < 16; msk <<= 1) {
        e += __shfl_xor(e, msk);
        p += __shfl_xor(p, msk);
      }
      if ((lane & 15) == 0) {
        int row = wr * 64 + m * 16 + ((lane >> 4) << 2) + r;
        e_part[wc][row] = e;
        p_part[wc][row] = p;
      }
    }
  __syncthreads();
  if (tid < BM) {
    float e = e_part[0][tid] + e_part[1][tid];
    float p = p_part[0][tid] + p_part[1][tid];
    size_t off = (size_t)bx * N + rowA0 + tid;
    part_e[off] = e;
    part_p[off] = p;
  }
}

// ---------------- kernel 4: per-row loss + block partial sums ----------------
__global__ __launch_bounds__(256) void k_final(
    const float* __restrict__ part_e, const float* __restrict__ part_p,
    const int* __restrict__ labels, const int* __restrict__ hist,
    float* __restrict__ bsum) {
  const int i = blockIdx.x * 256 + threadIdx.x;
  float e = 0.0f, p = 0.0f;
  #pragma unroll 8
  for (int cb = 0; cb < NCB; ++cb) {
    e += part_e[(size_t)cb * N + i];
    p += part_p[(size_t)cb * N + i];
  }
  float cnt = (float)hist[labels[i]];
  float li = logf(e) - p / cnt;
  #pragma unroll
  for (int m = 1; m < 64; m <<= 1) li += __shfl_xor(li, m);
  __shared__ float red[4];
  if ((threadIdx.x & 63) == 0) red[threadIdx.x >> 6] = li;
  __syncthreads();
  if (threadIdx.x == 0) bsum[blockIdx.x] = red[0] + red[1] + red[2] + red[3];
}

// ---------------- kernel 5: final scalar ----------------
__global__ void k_sum(const float* __restrict__ bsum, float* __restrict__ out) {
  float v = (threadIdx.x < (N / 256)) ? bsum[threadIdx.x] : 0.0f;
  #pragma unroll
  for (int m = 1; m < 64; m <<= 1) v += __shfl_xor(v, m);
  if (threadIdx.x == 0) out[0] = v * (1.0f / (float)N);
}

extern "C" void kernel_launch(void* const* d_in, const int* in_sizes, int n_in,
                              void* d_out, int out_size, void* d_ws, size_t ws_size,
                              hipStream_t stream) {
  const float* x = (const float*)d_in[0];
  const int* labels = (const int*)d_in[1];
  float* out = (float*)d_out;
  char* ws = (char*)d_ws;

  unsigned short* fb = (unsigned short*)ws;                       // 8 MB bf16 normalized
  float* part_e = (float*)(ws + (size_t)8  * 1024 * 1024);        // 2 MB
  float* part_p = (float*)(ws + (size_t)10 * 1024 * 1024);        // 2 MB
  int*   hist   = (int*)  (ws + (size_t)12 * 1024 * 1024);        // 512 B
  float* bsum   = (float*)(ws + (size_t)12 * 1024 * 1024 + 4096); // 128 B

  k_normalize<<<N, 64, 0, stream>>>(x, fb);
  k_hist<<<1, 256, 0, stream>>>(labels, hist);
  dim3 g(NCB, N / BM);
  k_gemm<<<g, 256, 0, stream>>>(fb, labels, part_e, part_p);
  k_final<<<N / 256, 256, 0, stream>>>(part_e, part_p, labels, hist, bsum);
  k_sum<<<1, 64, 0, stream>>>(bsum, out);
}

// Round 2
// 103.318 us; speedup vs baseline: 1.1771x; 1.1771x over previous
//
#include <hip/hip_runtime.h>
#include <hip/hip_bf16.h>

#define N 8192
#define D 512
#define BM 128
#define BN 128
#define BK 64
#define NCB (N / BN)   // 64 column blocks
#define NKT (D / BK)   // 8 K tiles
#define NTRI (NCB * (NCB + 1) / 2)  // 2080 upper-triangle blocks
#define INVT 14.285714285714286f

typedef __attribute__((ext_vector_type(8))) short bf16x8;
typedef __attribute__((ext_vector_type(4))) float f32x4;
typedef __attribute__((ext_vector_type(8))) unsigned short u16x8;

__device__ __forceinline__ unsigned short f2bf(float f) {
  __hip_bfloat16 h = __float2bfloat16(f);
  return *reinterpret_cast<unsigned short*>(&h);
}

// ---------------- kernel 1: L2-normalize rows, cast to bf16 ----------------
__global__ __launch_bounds__(256) void k_normalize(const float* __restrict__ x,
                                                   unsigned short* __restrict__ fb) {
  const int row = blockIdx.x * 4 + (threadIdx.x >> 6);
  const int lane = threadIdx.x & 63;
  const float* rp = x + (size_t)row * D + lane * 8;
  float4 v0 = *reinterpret_cast<const float4*>(rp);
  float4 v1 = *reinterpret_cast<const float4*>(rp + 4);
  float s = v0.x*v0.x + v0.y*v0.y + v0.z*v0.z + v0.w*v0.w
          + v1.x*v1.x + v1.y*v1.y + v1.z*v1.z + v1.w*v1.w;
  #pragma unroll
  for (int m = 1; m < 64; m <<= 1) s += __shfl_xor(s, m);
  float inv = 1.0f / fmaxf(sqrtf(s), 1e-12f);
  u16x8 o;
  o[0] = f2bf(v0.x*inv); o[1] = f2bf(v0.y*inv); o[2] = f2bf(v0.z*inv); o[3] = f2bf(v0.w*inv);
  o[4] = f2bf(v1.x*inv); o[5] = f2bf(v1.y*inv); o[6] = f2bf(v1.z*inv); o[7] = f2bf(v1.w*inv);
  *reinterpret_cast<u16x8*>(fb + (size_t)row * D + lane * 8) = o;
}

// ---------------- kernel 2: label histogram (pos counts) ----------------
__global__ __launch_bounds__(256) void k_hist(const int* __restrict__ labels,
                                              int* __restrict__ hist) {
  __shared__ int h[128];
  int tid = threadIdx.x;
  if (tid < 128) h[tid] = 0;
  __syncthreads();
  int i = blockIdx.x * 256 + tid;
  atomicAdd(&h[labels[i]], 1);
  __syncthreads();
  if (tid < 128 && h[tid]) atomicAdd(&hist[tid], h[tid]);
}

// ---------------- kernel 3: fused GEMM + exp-rowsum + masked-sum ----------------
// Upper-triangle only: block t -> (bx, by), by <= bx. Off-diagonal blocks emit
// BOTH row-partials (rows of by-block, summed over columns) and col-partials
// (rows of bx-block, summed over rows of the tile — symmetry of sim).
// part slot layout: slot bx <- rows rowA0..  (row-partials)
//                   slot by <- rows rowB0..  (col-partials)
// Each (slot, row-block) pair is written by exactly one block.
#define GLOAD_LDS16(g, l) __builtin_amdgcn_global_load_lds( \
    (const __attribute__((address_space(1))) unsigned int*)(g), \
    (__attribute__((address_space(3))) unsigned int*)(l), 16, 0, 0)

__global__ __launch_bounds__(256, 4) void k_gemm(
    const unsigned short* __restrict__ fb, const int* __restrict__ labels,
    float* __restrict__ part_e, float* __restrict__ part_p) {
  __shared__ __align__(16) short As[BM * BK];
  __shared__ __align__(16) short Bs[BN * BK];
  __shared__ float e_part[2][BM];   // row-partials, indexed by wc
  __shared__ float p_part[2][BM];
  __shared__ float e_cpart[2][BN];  // col-partials, indexed by wr
  __shared__ float p_cpart[2][BN];
  __shared__ int labR[BM];
  __shared__ int labC[BN];

  const int tid = threadIdx.x;
  const int lane = tid & 63;
  const int w = tid >> 6;
  const int wr = w >> 1, wc = w & 1;

  // triangle index -> (bx, by), by <= bx
  const int t = blockIdx.x;
  int bx = (int)((sqrtf(8.0f * (float)t + 1.0f) - 1.0f) * 0.5f);
  while ((bx + 1) * (bx + 2) / 2 <= t) ++bx;
  while (bx * (bx + 1) / 2 > t) --bx;
  const int by = t - bx * (bx + 1) / 2;
  const bool offdiag = (bx != by);

  const int rowA0 = by * BM, rowB0 = bx * BN;

  if (tid < BM) labR[tid] = labels[rowA0 + tid];
  else          labC[tid - BM] = labels[rowB0 + (tid - BM)];

  f32x4 acc[4][4] = {};
  const int sslot = tid & 7;

  for (int kt = 0; kt < NKT; ++kt) {
    if (kt) __syncthreads();
    const int kbase = kt * BK;
    #pragma unroll
    for (int it = 0; it < 4; ++it) {
      int r = (it * 256 + tid) >> 3;
      int kcol = ((sslot ^ (r & 7)) << 3) + kbase;
      GLOAD_LDS16(fb + (size_t)(rowA0 + r) * D + kcol,
                  (char*)As + it * 4096 + w * 1024);
    }
    #pragma unroll
    for (int it = 0; it < 4; ++it) {
      int r = (it * 256 + tid) >> 3;
      int kcol = ((sslot ^ (r & 7)) << 3) + kbase;
      GLOAD_LDS16(fb + (size_t)(rowB0 + r) * D + kcol,
                  (char*)Bs + it * 4096 + w * 1024);
    }
    __syncthreads();

    #pragma unroll
    for (int kk = 0; kk < BK; kk += 32) {
      bf16x8 af[4], bg[4];
      #pragma unroll
      for (int m = 0; m < 4; ++m) {
        int ar = wr * 64 + m * 16 + (lane & 15);
        int kb = (kk + ((lane >> 4) << 3)) * 2;
        af[m] = *reinterpret_cast<const bf16x8*>(
            (const char*)As + ar * 128 + (kb ^ ((ar & 7) << 4)));
      }
      #pragma unroll
      for (int n = 0; n < 4; ++n) {
        int br = wc * 64 + n * 16 + (lane & 15);
        int kb = (kk + ((lane >> 4) << 3)) * 2;
        bg[n] = *reinterpret_cast<const bf16x8*>(
            (const char*)Bs + br * 128 + (kb ^ ((br & 7) << 4)));
      }
      #pragma unroll
      for (int m = 0; m < 4; ++m)
        #pragma unroll
        for (int n = 0; n < 4; ++n)
          acc[m][n] = __builtin_amdgcn_mfma_f32_16x16x32_bf16(af[m], bg[n], acc[m][n], 0, 0, 0);
    }
  }

  // ---- fused epilogue ----
  float esum[4][4] = {};   // per (m, r): row-partial over this tile's columns
  float psum[4][4] = {};
  float ecol[4] = {};      // per n: col-partial over this tile's rows (in-thread part)
  float pcol[4] = {};
  int lr[4][4];
  #pragma unroll
  for (int m = 0; m < 4; ++m)
    #pragma unroll
    for (int r = 0; r < 4; ++r)
      lr[m][r] = labR[wr * 64 + m * 16 + ((lane >> 4) << 2) + r];

  #pragma unroll
  for (int n = 0; n < 4; ++n) {
    int lc = labC[wc * 64 + n * 16 + (lane & 15)];
    #pragma unroll
    for (int m = 0; m < 4; ++m)
      #pragma unroll
      for (int r = 0; r < 4; ++r) {
        float s = acc[m][n][r] * INVT;
        float e = __expf(s);
        float pm = (lr[m][r] == lc) ? s : 0.0f;
        esum[m][r] += e;
        psum[m][r] += pm;
        ecol[n] += e;
        pcol[n] += pm;
      }
  }

  // row-partials: reduce over the 16 lanes (columns) of each group + over n (done)
  #pragma unroll
  for (int m = 0; m < 4; ++m)
    #pragma unroll
    for (int r = 0; r < 4; ++r) {
      float e = esum[m][r], p = psum[m][r];
      #pragma unroll
      for (int msk = 1; msk < 16; msk <<= 1) {
        e += __shfl_xor(e, msk);
        p += __shfl_xor(p, msk);
      }
      if ((lane & 15) == 0) {
        int row = wr * 64 + m * 16 + ((lane >> 4) << 2) + r;
        e_part[wc][row] = e;
        p_part[wc][row] = p;
      }
    }

  // col-partials: reduce across the 4 row-groups (lane>>4)
  if (offdiag) {
    #pragma unroll
    for (int n = 0; n < 4; ++n) {
      float e = ecol[n], p = pcol[n];
      e += __shfl_xor(e, 16); e += __shfl_xor(e, 32);
      p += __shfl_xor(p, 16); p += __shfl_xor(p, 32);
      if ((lane >> 4) == 0) {
        int c = wc * 64 + n * 16 + (lane & 15);
        e_cpart[wr][c] = e;
        p_cpart[wr][c] = p;
      }
    }
  }
  __syncthreads();

  if (tid < BM) {
    float e = e_part[0][tid] + e_part[1][tid];
    float p = p_part[0][tid] + p_part[1][tid];
    size_t off = (size_t)bx * N + rowA0 + tid;
    part_e[off] = e;
    part_p[off] = p;
  } else if (offdiag) {
    int c = tid - BM;
    float e = e_cpart[0][c] + e_cpart[1][c];
    float p = p_cpart[0][c] + p_cpart[1][c];
    size_t off = (size_t)by * N + rowB0 + c;
    part_e[off] = e;
    part_p[off] = p;
  }
}

// ---------------- kernel 4: per-row loss + block partial sums ----------------
__global__ __launch_bounds__(256) void k_final(
    const float* __restrict__ part_e, const float* __restrict__ part_p,
    const int* __restrict__ labels, const int* __restrict__ hist,
    float* __restrict__ bsum) {
  const int i = blockIdx.x * 256 + threadIdx.x;
  float e = 0.0f, p = 0.0f;
  #pragma unroll 8
  for (int cb = 0; cb < NCB; ++cb) {
    e += part_e[(size_t)cb * N + i];
    p += part_p[(size_t)cb * N + i];
  }
  float cnt = (float)hist[labels[i]];
  float li = logf(e) - p / cnt;
  #pragma unroll
  for (int m = 1; m < 64; m <<= 1) li += __shfl_xor(li, m);
  __shared__ float red[4];
  if ((threadIdx.x & 63) == 0) red[threadIdx.x >> 6] = li;
  __syncthreads();
  if (threadIdx.x == 0) bsum[blockIdx.x] = red[0] + red[1] + red[2] + red[3];
}

// ---------------- kernel 5: final scalar ----------------
__global__ void k_sum(const float* __restrict__ bsum, float* __restrict__ out) {
  float v = (threadIdx.x < (N / 256)) ? bsum[threadIdx.x] : 0.0f;
  #pragma unroll
  for (int m = 1; m < 64; m <<= 1) v += __shfl_xor(v, m);
  if (threadIdx.x == 0) out[0] = v * (1.0f / (float)N);
}

extern "C" void kernel_launch(void* const* d_in, const int* in_sizes, int n_in,
                              void* d_out, int out_size, void* d_ws, size_t ws_size,
                              hipStream_t stream) {
  const float* x = (const float*)d_in[0];
  const int* labels = (const int*)d_in[1];
  float* out = (float*)d_out;
  char* ws = (char*)d_ws;

  unsigned short* fb = (unsigned short*)ws;                       // 8 MB bf16 normalized
  float* part_e = (float*)(ws + (size_t)8  * 1024 * 1024);        // 2 MB
  float* part_p = (float*)(ws + (size_t)10 * 1024 * 1024);        // 2 MB
  int*   hist   = (int*)  (ws + (size_t)12 * 1024 * 1024);        // 512 B
  float* bsum   = (float*)(ws + (size_t)12 * 1024 * 1024 + 4096); // 128 B

  hipMemsetAsync(hist, 0, 512, stream);
  k_normalize<<<N / 4, 256, 0, stream>>>(x, fb);
  k_hist<<<N / 256, 256, 0, stream>>>(labels, hist);
  k_gemm<<<NTRI, 256, 0, stream>>>(fb, labels, part_e, part_p);
  k_final<<<N / 256, 256, 0, stream>>>(part_e, part_p, labels, hist, bsum);
  k_sum<<<1, 64, 0, stream>>>(bsum, out);
}

// Round 3
// 84.109 us; speedup vs baseline: 1.4460x; 1.2284x over previous
//
#include <hip/hip_runtime.h>
#include <hip/hip_bf16.h>

#define N 8192
#define D 512
#define BM 128
#define BN 128
#define BK 64
#define NCB (N / BN)   // 64 column blocks
#define NKT (D / BK)   // 8 K tiles
#define NTRI (NCB * (NCB + 1) / 2)  // 2080 upper-triangle blocks
#define INVT 14.285714285714286f

typedef __attribute__((ext_vector_type(8))) short bf16x8;
typedef __attribute__((ext_vector_type(4))) float f32x4;
typedef __attribute__((ext_vector_type(8))) unsigned short u16x8;

__device__ __forceinline__ unsigned short f2bf(float f) {
  __hip_bfloat16 h = __float2bfloat16(f);
  return *reinterpret_cast<unsigned short*>(&h);
}

// ---------------- kernel 1: L2-normalize rows, cast to bf16 ----------------
__global__ __launch_bounds__(256) void k_normalize(const float* __restrict__ x,
                                                   unsigned short* __restrict__ fb) {
  const int row = blockIdx.x * 4 + (threadIdx.x >> 6);
  const int lane = threadIdx.x & 63;
  const float* rp = x + (size_t)row * D + lane * 8;
  float4 v0 = *reinterpret_cast<const float4*>(rp);
  float4 v1 = *reinterpret_cast<const float4*>(rp + 4);
  float s = v0.x*v0.x + v0.y*v0.y + v0.z*v0.z + v0.w*v0.w
          + v1.x*v1.x + v1.y*v1.y + v1.z*v1.z + v1.w*v1.w;
  #pragma unroll
  for (int m = 1; m < 64; m <<= 1) s += __shfl_xor(s, m);
  float inv = 1.0f / fmaxf(sqrtf(s), 1e-12f);
  u16x8 o;
  o[0] = f2bf(v0.x*inv); o[1] = f2bf(v0.y*inv); o[2] = f2bf(v0.z*inv); o[3] = f2bf(v0.w*inv);
  o[4] = f2bf(v1.x*inv); o[5] = f2bf(v1.y*inv); o[6] = f2bf(v1.z*inv); o[7] = f2bf(v1.w*inv);
  *reinterpret_cast<u16x8*>(fb + (size_t)row * D + lane * 8) = o;
}

// ---------------- kernel 2: label histogram (pos counts) ----------------
__global__ __launch_bounds__(256) void k_hist(const int* __restrict__ labels,
                                              int* __restrict__ hist) {
  __shared__ int h[128];
  int tid = threadIdx.x;
  if (tid < 128) h[tid] = 0;
  __syncthreads();
  int i = blockIdx.x * 256 + tid;
  atomicAdd(&h[labels[i]], 1);
  __syncthreads();
  if (tid < 128 && h[tid]) atomicAdd(&hist[tid], h[tid]);
}

// ---------------- kernel 3: fused GEMM + exp-rowsum + masked-sum ----------------
// Upper-triangle only: block t -> (bx, by), by <= bx. Off-diagonal blocks emit
// BOTH row-partials (rows of by-block, summed over tile columns) and
// col-partials (rows of bx-block, via symmetry of sim).
// part slot layout: slot bx <- rows rowA0.. ; slot by <- rows rowB0..
// Each (slot, row-block) pair is written by exactly one block.
#define GLOAD_LDS16(g, l) __builtin_amdgcn_global_load_lds( \
    (const __attribute__((address_space(1))) unsigned int*)(g), \
    (__attribute__((address_space(3))) unsigned int*)(l), 16, 0, 0)

// (256,3): 3 blocks/CU. LDS 37.9KB*3=114KB fits 160KB; VGPR budget ~170/wave
// — round-1 usage (76 VGPR + 64 AGPR) fits with slack. (256,4) spilled:
// 99MB scratch writes/dispatch, MfmaUtil 17%. // R2 post-mortem
__global__ __launch_bounds__(256, 3) void k_gemm(
    const unsigned short* __restrict__ fb, const int* __restrict__ labels,
    float* __restrict__ part_e, float* __restrict__ part_p) {
  __shared__ __align__(16) short As[BM * BK];
  __shared__ __align__(16) short Bs[BN * BK];
  __shared__ float e_part[2][BM];   // row-partials, indexed by wc
  __shared__ float p_part[2][BM];
  __shared__ float e_cpart[2][BN];  // col-partials, indexed by wr
  __shared__ float p_cpart[2][BN];
  __shared__ int labR[BM];
  __shared__ int labC[BN];

  const int tid = threadIdx.x;
  const int lane = tid & 63;
  const int w = tid >> 6;
  const int wr = w >> 1, wc = w & 1;

  // triangle index -> (bx, by), by <= bx
  const int t = blockIdx.x;
  int bx = (int)((sqrtf(8.0f * (float)t + 1.0f) - 1.0f) * 0.5f);
  while ((bx + 1) * (bx + 2) / 2 <= t) ++bx;
  while (bx * (bx + 1) / 2 > t) --bx;
  const int by = t - bx * (bx + 1) / 2;
  const bool offdiag = (bx != by);

  const int rowA0 = by * BM, rowB0 = bx * BN;

  if (tid < BM) labR[tid] = labels[rowA0 + tid];
  else          labC[tid - BM] = labels[rowB0 + (tid - BM)];

  f32x4 acc[4][4] = {};
  const int sslot = tid & 7;

  for (int kt = 0; kt < NKT; ++kt) {
    if (kt) __syncthreads();
    const int kbase = kt * BK;
    #pragma unroll
    for (int it = 0; it < 4; ++it) {
      int r = (it * 256 + tid) >> 3;
      int kcol = ((sslot ^ (r & 7)) << 3) + kbase;
      GLOAD_LDS16(fb + (size_t)(rowA0 + r) * D + kcol,
                  (char*)As + it * 4096 + w * 1024);
    }
    #pragma unroll
    for (int it = 0; it < 4; ++it) {
      int r = (it * 256 + tid) >> 3;
      int kcol = ((sslot ^ (r & 7)) << 3) + kbase;
      GLOAD_LDS16(fb + (size_t)(rowB0 + r) * D + kcol,
                  (char*)Bs + it * 4096 + w * 1024);
    }
    __syncthreads();

    #pragma unroll
    for (int kk = 0; kk < BK; kk += 32) {
      bf16x8 af[4], bg[4];
      #pragma unroll
      for (int m = 0; m < 4; ++m) {
        int ar = wr * 64 + m * 16 + (lane & 15);
        int kb = (kk + ((lane >> 4) << 3)) * 2;
        af[m] = *reinterpret_cast<const bf16x8*>(
            (const char*)As + ar * 128 + (kb ^ ((ar & 7) << 4)));
      }
      #pragma unroll
      for (int n = 0; n < 4; ++n) {
        int br = wc * 64 + n * 16 + (lane & 15);
        int kb = (kk + ((lane >> 4) << 3)) * 2;
        bg[n] = *reinterpret_cast<const bf16x8*>(
            (const char*)Bs + br * 128 + (kb ^ ((br & 7) << 4)));
      }
      #pragma unroll
      for (int m = 0; m < 4; ++m)
        #pragma unroll
        for (int n = 0; n < 4; ++n)
          acc[m][n] = __builtin_amdgcn_mfma_f32_16x16x32_bf16(af[m], bg[n], acc[m][n], 0, 0, 0);
    }
  }

  // ---- fused epilogue (low register pressure: scalar e/p per (m,r)) ----
  float ecol[4] = {};
  float pcol[4] = {};
  int lc[4];
  #pragma unroll
  for (int n = 0; n < 4; ++n)
    lc[n] = labC[wc * 64 + n * 16 + (lane & 15)];

  #pragma unroll
  for (int m = 0; m < 4; ++m)
    #pragma unroll
    for (int r = 0; r < 4; ++r) {
      int lrv = labR[wr * 64 + m * 16 + ((lane >> 4) << 2) + r];
      float e = 0.0f, p = 0.0f;
      #pragma unroll
      for (int n = 0; n < 4; ++n) {
        float s = acc[m][n][r] * INVT;
        float ex = __expf(s);
        float pm = (lrv == lc[n]) ? s : 0.0f;
        e += ex; p += pm;
        ecol[n] += ex; pcol[n] += pm;
      }
      #pragma unroll
      for (int msk = 1; msk < 16; msk <<= 1) {
        e += __shfl_xor(e, msk);
        p += __shfl_xor(p, msk);
      }
      if ((lane & 15) == 0) {
        int row = wr * 64 + m * 16 + ((lane >> 4) << 2) + r;
        e_part[wc][row] = e;
        p_part[wc][row] = p;
      }
    }

  // col-partials: reduce across the 4 row-groups (lane>>4)
  if (offdiag) {
    #pragma unroll
    for (int n = 0; n < 4; ++n) {
      float e = ecol[n], p = pcol[n];
      e += __shfl_xor(e, 16); e += __shfl_xor(e, 32);
      p += __shfl_xor(p, 16); p += __shfl_xor(p, 32);
      if ((lane >> 4) == 0) {
        int c = wc * 64 + n * 16 + (lane & 15);
        e_cpart[wr][c] = e;
        p_cpart[wr][c] = p;
      }
    }
  }
  __syncthreads();

  if (tid < BM) {
    float e = e_part[0][tid] + e_part[1][tid];
    float p = p_part[0][tid] + p_part[1][tid];
    size_t off = (size_t)bx * N + rowA0 + tid;
    part_e[off] = e;
    part_p[off] = p;
  } else if (offdiag) {
    int c = tid - BM;
    float e = e_cpart[0][c] + e_cpart[1][c];
    float p = p_cpart[0][c] + p_cpart[1][c];
    size_t off = (size_t)by * N + rowB0 + c;
    part_e[off] = e;
    part_p[off] = p;
  }
}

// ---------------- kernel 4: per-row loss + block partial sums ----------------
__global__ __launch_bounds__(256) void k_final(
    const float* __restrict__ part_e, const float* __restrict__ part_p,
    const int* __restrict__ labels, const int* __restrict__ hist,
    float* __restrict__ bsum) {
  const int i = blockIdx.x * 256 + threadIdx.x;
  float e = 0.0f, p = 0.0f;
  #pragma unroll 8
  for (int cb = 0; cb < NCB; ++cb) {
    e += part_e[(size_t)cb * N + i];
    p += part_p[(size_t)cb * N + i];
  }
  float cnt = (float)hist[labels[i]];
  float li = logf(e) - p / cnt;
  #pragma unroll
  for (int m = 1; m < 64; m <<= 1) li += __shfl_xor(li, m);
  __shared__ float red[4];
  if ((threadIdx.x & 63) == 0) red[threadIdx.x >> 6] = li;
  __syncthreads();
  if (threadIdx.x == 0) bsum[blockIdx.x] = red[0] + red[1] + red[2] + red[3];
}

// ---------------- kernel 5: final scalar ----------------
__global__ void k_sum(const float* __restrict__ bsum, float* __restrict__ out) {
  float v = (threadIdx.x < (N / 256)) ? bsum[threadIdx.x] : 0.0f;
  #pragma unroll
  for (int m = 1; m < 64; m <<= 1) v += __shfl_xor(v, m);
  if (threadIdx.x == 0) out[0] = v * (1.0f / (float)N);
}

extern "C" void kernel_launch(void* const* d_in, const int* in_sizes, int n_in,
                              void* d_out, int out_size, void* d_ws, size_t ws_size,
                              hipStream_t stream) {
  const float* x = (const float*)d_in[0];
  const int* labels = (const int*)d_in[1];
  float* out = (float*)d_out;
  char* ws = (char*)d_ws;

  unsigned short* fb = (unsigned short*)ws;                       // 8 MB bf16 normalized
  float* part_e = (float*)(ws + (size_t)8  * 1024 * 1024);        // 2 MB
  float* part_p = (float*)(ws + (size_t)10 * 1024 * 1024);        // 2 MB
  int*   hist   = (int*)  (ws + (size_t)12 * 1024 * 1024);        // 512 B
  float* bsum   = (float*)(ws + (size_t)12 * 1024 * 1024 + 4096); // 128 B

  hipMemsetAsync(hist, 0, 512, stream);
  k_normalize<<<N / 4, 256, 0, stream>>>(x, fb);
  k_hist<<<N / 256, 256, 0, stream>>>(labels, hist);
  k_gemm<<<NTRI, 256, 0, stream>>>(fb, labels, part_e, part_p);
  k_final<<<N / 256, 256, 0, stream>>>(part_e, part_p, labels, hist, bsum);
  k_sum<<<1, 64, 0, stream>>>(bsum, out);
}